// Round 8
// baseline (252.499 us; speedup 1.0000x reference)
//
#include <hip/hip_runtime.h>
#include <hip/hip_bf16.h>

#define N_NODES 50000
#define E_EDGES 400000
#define IN_CH   256
#define HEADS   4
#define OUT_CH  64
#define HID     256
#define ALPHA   0.2f
#define LN_EPS  1e-5f

using f32x16 = __attribute__((ext_vector_type(16))) float;
using bf16x8 = __attribute__((ext_vector_type(8))) short;   // 8 bf16 (4 VGPRs)
using u16x8  = __attribute__((ext_vector_type(8))) unsigned short;
using u16x4  = __attribute__((ext_vector_type(4))) unsigned short;

typedef __attribute__((address_space(3))) void* lds_vp;
typedef const __attribute__((address_space(1))) void* gbl_vp;

__device__ __forceinline__ unsigned short f2bf(float f) {
    __hip_bfloat16 b = __float2bfloat16(f);
    return *(unsigned short*)&b;
}
__device__ __forceinline__ float bf2f(unsigned short u) {
    __hip_bfloat16 b = *(__hip_bfloat16*)&u;
    return __bfloat162float(b);
}

// ------------------------------------------------------------------ prep
__global__ __launch_bounds__(256) void prep_kernel(
    const float* __restrict__ W, const float* __restrict__ ffn_w,
    unsigned short* __restrict__ Wt, unsigned short* __restrict__ Ft)
{
    int i = blockIdx.x * 256 + threadIdx.x;
    if (i < 65536) {
        int n = i >> 8, k = i & 255;
        Wt[i] = f2bf(W[k * 256 + n]);
    } else {
        int j = i - 65536;
        int n = j >> 8, k = j & 255;
        Ft[j] = f2bf(ffn_w[k * 256 + n]);
    }
}

// ------------------------------------------------------------------ B-resident GEMM
// C[M,256] = A[M,256] @ B; Bt[n][k] bf16 staged entirely in LDS (128 KiB) once.
// One barrier total; each wave independently streams a 32-row A strip with a
// 4-deep register prefetch pipeline and mfma_f32_32x32x16_bf16.
// SCORES (GEMM1): fused s_src/s_dst epilogue from f32 accumulators.
template<bool A_IS_F32, bool RELU_BIAS, bool SCORES>
__global__ __launch_bounds__(512, 2) void gemm_bres(
    const void* __restrict__ Av, const unsigned short* __restrict__ Bt,
    const float* __restrict__ bias, const float* __restrict__ attn_fc,
    void* __restrict__ Cv, float* __restrict__ s_src, float* __restrict__ s_dst,
    int M)
{
    __shared__ unsigned short Bs[256 * 256];   // 128 KiB

    const int tid = threadIdx.x;
    const int lane = tid & 63, wid = tid >> 6;

    // ---- stage all of B: linear LDS dest, inverse-swizzled global source
    #pragma unroll
    for (int i = 0; i < 16; i++) {
        int d = i * 512 + tid;                 // 16B-chunk id, 0..8191
        int n = d >> 5, cp = d & 31;
        int cs = cp ^ (n & 31);
        const unsigned short* g = Bt + (size_t)n * 256 + cs * 8;
        __builtin_amdgcn_global_load_lds((gbl_vp)g, (lds_vp)&Bs[(size_t)d * 8],
                                         16, 0, 0);
    }
    __syncthreads();

    const int strip = wid * 256 + blockIdx.x;  // interleaved for CU balance
    const int r0 = strip * 32;
    if (r0 >= M) return;

    const int q5 = lane & 31, kg = lane >> 5;
    const int rowc = min(r0 + q5, M - 1);      // clamped for tail strip

    f32x16 acc[8] = {};

    const float* Af = (const float*)Av;
    const unsigned short* Ab = (const unsigned short*)Av;

    // ---- 4-deep A prefetch pipeline (slots statically indexed via unroll)
    float4 pa[4], pb[4]; u16x8 pc[4];
    auto loadA = [&](int t, int slot) {
        if (A_IS_F32) {
            const float* p = Af + (size_t)rowc * 256 + t * 16 + kg * 8;
            pa[slot] = *(const float4*)p; pb[slot] = *(const float4*)(p + 4);
        } else {
            pc[slot] = *(const u16x8*)(Ab + (size_t)rowc * 256 + t * 16 + kg * 8);
        }
    };
    loadA(0, 0); loadA(1, 1); loadA(2, 2); loadA(3, 3);

    #pragma unroll
    for (int t = 0; t < 16; t++) {
        const int slot = t & 3;
        bf16x8 af;
        if (A_IS_F32) {
            union { unsigned int u[4]; bf16x8 v; } cv;
            cv.u[0] = (unsigned)f2bf(pa[slot].x) | ((unsigned)f2bf(pa[slot].y) << 16);
            cv.u[1] = (unsigned)f2bf(pa[slot].z) | ((unsigned)f2bf(pa[slot].w) << 16);
            cv.u[2] = (unsigned)f2bf(pb[slot].x) | ((unsigned)f2bf(pb[slot].y) << 16);
            cv.u[3] = (unsigned)f2bf(pb[slot].z) | ((unsigned)f2bf(pb[slot].w) << 16);
            af = cv.v;
        } else {
            union { u16x8 u; bf16x8 v; } cv; cv.u = pc[slot]; af = cv.v;
        }
        if (t + 4 < 16) loadA(t + 4, slot);    // refill consumed slot early
        #pragma unroll
        for (int n = 0; n < 8; n++) {
            const bf16x8 bf = *(const bf16x8*)((const char*)Bs +
                (size_t)(n * 32 + q5) * 512 + (((t * 2 + kg) ^ q5) * 16));
            acc[n] = __builtin_amdgcn_mfma_f32_32x32x16_bf16(af, bf, acc[n], 0, 0, 0);
        }
    }

    // ---- epilogue.  D layout: col = lane&31, row = (reg&3)+8*(reg>>2)+4*kg
    #pragma unroll
    for (int n = 0; n < 8; n++) {
        int gc = n * 32 + q5;
        float bv = RELU_BIAS ? bias[gc] : 0.f;
        #pragma unroll
        for (int reg = 0; reg < 16; reg++) {
            int rl = (reg & 3) + 8 * (reg >> 2) + 4 * kg;
            int gr = r0 + rl;
            if (gr >= M) continue;
            float v = acc[n][reg];
            if (RELU_BIAS) {
                v += bv; v = v > 0.f ? v : 0.f;
                ((float*)Cv)[(size_t)gr * 256 + gc] = v;
            } else {
                ((unsigned short*)Cv)[(size_t)gr * 256 + gc] = f2bf(v);
            }
        }
    }

    // ---- fused attention scores (GEMM1): row gr's 256 cols live across the
    // 32 lanes of this kg-half (8 cols each). head = n>>1, d = (n&1)*32+q5.
    if (SCORES) {
        float as_[8], ad_[8];
        #pragma unroll
        for (int n = 0; n < 8; n++) {
            int head = n >> 1, d = (n & 1) * 32 + q5;
            as_[n] = attn_fc[head * 128 + d];
            ad_[n] = attn_fc[head * 128 + 64 + d];
        }
        #pragma unroll
        for (int reg = 0; reg < 16; reg++) {
            int gr = r0 + (reg & 3) + 8 * (reg >> 2) + 4 * kg;
            float ps[4] = {}, pd[4] = {};
            #pragma unroll
            for (int n = 0; n < 8; n++) {
                ps[n >> 1] += acc[n][reg] * as_[n];
                pd[n >> 1] += acc[n][reg] * ad_[n];
            }
            #pragma unroll
            for (int off = 16; off; off >>= 1) {
                #pragma unroll
                for (int hh = 0; hh < 4; hh++) {
                    ps[hh] += __shfl_xor(ps[hh], off, 32);
                    pd[hh] += __shfl_xor(pd[hh], off, 32);
                }
            }
            if (q5 == 0 && gr < M) {
                *(float4*)(s_src + (size_t)gr * 4) = make_float4(ps[0], ps[1], ps[2], ps[3]);
                *(float4*)(s_dst + (size_t)gr * 4) = make_float4(pd[0], pd[1], pd[2], pd[3]);
            }
        }
    }
}

// ------------------------------------------------------------------ histogram
__global__ void hist_kernel(const int* __restrict__ erow, int* __restrict__ counts) {
    int e = blockIdx.x * blockDim.x + threadIdx.x;
    if (e < E_EDGES) atomicAdd(&counts[erow[e]], 1);
}

// ------------------------------------------------------------------ 3-pass scan
__global__ __launch_bounds__(256) void scanA_kernel(
    const int* __restrict__ counts, int* __restrict__ bsum)
{
    const int b = blockIdx.x, tid = threadIdx.x;
    int i0 = b * 512 + tid;
    int v = 0;
    if (i0 < N_NODES) v += counts[i0];
    if (i0 + 256 < N_NODES) v += counts[i0 + 256];
    #pragma unroll
    for (int off = 32; off; off >>= 1) v += __shfl_xor(v, off, 64);
    __shared__ int ws[4];
    if ((tid & 63) == 0) ws[tid >> 6] = v;
    __syncthreads();
    if (tid == 0) bsum[b] = ws[0] + ws[1] + ws[2] + ws[3];
}

__global__ __launch_bounds__(128) void scanB_kernel(
    const int* __restrict__ bsum, int* __restrict__ bscan, int nb)
{
    const int tid = threadIdx.x;
    const int lane = tid & 63, wid = tid >> 6;
    int val = (tid < nb) ? bsum[tid] : 0;
    int x = val;
    #pragma unroll
    for (int off = 1; off < 64; off <<= 1) {
        int y = __shfl_up(x, off, 64);
        if (lane >= off) x += y;
    }
    __shared__ int w0;
    if (tid == 63) w0 = x;
    __syncthreads();
    if (wid == 1) x += w0;
    if (tid < nb) bscan[tid] = x - val;
}

__global__ __launch_bounds__(512) void scanC_kernel(
    const int* __restrict__ counts, const int* __restrict__ bscan,
    int* __restrict__ offsets, int* __restrict__ cursor)
{
    const int b = blockIdx.x, tid = threadIdx.x;
    const int lane = tid & 63, wid = tid >> 6;
    const int i = b * 512 + tid;
    int v = (i < N_NODES) ? counts[i] : 0;
    int x = v;
    #pragma unroll
    for (int off = 1; off < 64; off <<= 1) {
        int y = __shfl_up(x, off, 64);
        if (lane >= off) x += y;
    }
    __shared__ int ws[8];
    if (lane == 63) ws[wid] = x;
    __syncthreads();
    if (wid == 0 && lane < 8) {
        int s = ws[lane];
        #pragma unroll
        for (int off = 1; off < 8; off <<= 1) {
            int y = __shfl_up(s, off, 8);
            if ((lane & 7) >= off) s += y;
        }
        ws[lane] = s;
    }
    __syncthreads();
    int prefix = (wid ? ws[wid - 1] : 0) + bscan[b];
    int excl = prefix + x - v;
    if (i < N_NODES) { offsets[i] = excl; cursor[i] = excl; }
    if (i == N_NODES - 1) offsets[N_NODES] = excl + v;
}

// ------------------------------------------------------------------ scatter + weight precompute
__global__ __launch_bounds__(256) void scatter_kernel(
    const int* __restrict__ erow, const int* __restrict__ ecol,
    const float* __restrict__ s_src, const float* __restrict__ s_dst,
    int* __restrict__ cursor, int* __restrict__ sorted_col,
    float4* __restrict__ sorted_w)
{
    int e = blockIdx.x * blockDim.x + threadIdx.x;
    if (e >= E_EDGES) return;
    int r = erow[e], c = ecol[e];
    float4 ss = ((const float4*)s_src)[r];
    float4 sd = ((const float4*)s_dst)[c];
    float sc[4] = {ss.x + sd.x, ss.y + sd.y, ss.z + sd.z, ss.w + sd.w};
    float4 w;
    float* wp = (float*)&w;
    #pragma unroll
    for (int h = 0; h < 4; h++) {
        float v = sc[h] > 0.f ? sc[h] : ALPHA * sc[h];
        wp[h] = __expf(v);
    }
    int pos = atomicAdd(&cursor[r], 1);
    sorted_col[pos] = c;
    sorted_w[pos] = w;
}

// ------------------------------------------------------------------ aggregate + residual + LN
// one wave per node, 2 edges in parallel (lane halves), unroll 4 → 8 gathers
// in flight; lane owns 8 cols (u16x8).
__global__ __launch_bounds__(256) void aggregate_ln_kernel(
    const unsigned short* __restrict__ Wh, const float* __restrict__ sorted_w,
    const int* __restrict__ offsets, const int* __restrict__ sorted_col,
    const float* __restrict__ ln_gamma, const float* __restrict__ ln_beta,
    unsigned short* __restrict__ h_ln)
{
    const int lane = threadIdx.x & 63, wid = threadIdx.x >> 6;
    const int n = blockIdx.x * 4 + wid;
    const int p = lane >> 5;
    const int q5 = lane & 31;
    const int c0 = q5 * 8;
    const int h = q5 >> 3;
    const int beg = offsets[n], end = offsets[n + 1];

    float acc[8] = {};
    float wsum = 0.f;
    for (int base = beg; base < end; base += 64) {
        int cnt = min(64, end - base);
        int cv = (base + lane < end) ? sorted_col[base + lane] : 0;
        int jj = 0;
        #pragma unroll 4
        for (; jj + 2 <= cnt; jj += 2) {
            int c = __shfl(cv, jj + p, 64);
            float w = sorted_w[(size_t)(base + jj + p) * 4 + h];
            u16x8 r = *(const u16x8*)(Wh + (size_t)c * HID + c0);
            wsum += w;
            #pragma unroll
            for (int k = 0; k < 8; k++) acc[k] += w * bf2f(r[k]);
        }
        if (jj < cnt) {                        // odd tail edge: half-wave 0 only
            int c = __shfl(cv, jj, 64);
            if (p == 0) {
                float w = sorted_w[(size_t)(base + jj) * 4 + h];
                u16x8 r = *(const u16x8*)(Wh + (size_t)c * HID + c0);
                wsum += w;
                #pragma unroll
                for (int k = 0; k < 8; k++) acc[k] += w * bf2f(r[k]);
            }
        }
    }
    wsum += __shfl_xor(wsum, 32, 64);
    #pragma unroll
    for (int k = 0; k < 8; k++) acc[k] += __shfl_xor(acc[k], 32, 64);

    u16x8 rr = *(const u16x8*)(Wh + (size_t)n * HID + c0);
    float inv_w = 1.f / (wsum + 1e-15f);
    float val[8];
    float s = 0.f;
    #pragma unroll
    for (int k = 0; k < 8; k++) {
        val[k] = acc[k] * inv_w + bf2f(rr[k]);
        s += val[k];
    }
    #pragma unroll
    for (int off = 16; off; off >>= 1) s += __shfl_xor(s, off, 64);
    float mu = s * (1.f / HID);
    float s2 = 0.f;
    #pragma unroll
    for (int k = 0; k < 8; k++) { float d = val[k] - mu; s2 += d * d; }
    #pragma unroll
    for (int off = 16; off; off >>= 1) s2 += __shfl_xor(s2, off, 64);
    float inv_std = rsqrtf(s2 * (1.f / HID) + LN_EPS);

    if (p == 0) {
        float4 g0 = *(const float4*)(ln_gamma + c0);
        float4 g1 = *(const float4*)(ln_gamma + c0 + 4);
        float4 b0 = *(const float4*)(ln_beta + c0);
        float4 b1 = *(const float4*)(ln_beta + c0 + 4);
        u16x8 outv;
        outv[0] = f2bf((val[0] - mu) * inv_std * g0.x + b0.x);
        outv[1] = f2bf((val[1] - mu) * inv_std * g0.y + b0.y);
        outv[2] = f2bf((val[2] - mu) * inv_std * g0.z + b0.z);
        outv[3] = f2bf((val[3] - mu) * inv_std * g0.w + b0.w);
        outv[4] = f2bf((val[4] - mu) * inv_std * g1.x + b1.x);
        outv[5] = f2bf((val[5] - mu) * inv_std * g1.y + b1.y);
        outv[6] = f2bf((val[6] - mu) * inv_std * g1.z + b1.z);
        outv[7] = f2bf((val[7] - mu) * inv_std * g1.w + b1.w);
        *(u16x8*)(h_ln + (size_t)n * HID + c0) = outv;
    }
}

// ------------------------------------------------------------------ launch
extern "C" void kernel_launch(void* const* d_in, const int* in_sizes, int n_in,
                              void* d_out, int out_size, void* d_ws, size_t ws_size,
                              hipStream_t stream)
{
    const float* h        = (const float*)d_in[0];
    const int*   erow     = (const int*)  d_in[1];
    const int*   ecol     = (const int*)  d_in[2];
    const float* W        = (const float*)d_in[3];
    const float* attn_fc  = (const float*)d_in[4];
    const float* ln_gamma = (const float*)d_in[5];
    const float* ln_beta  = (const float*)d_in[6];
    const float* ffn_w    = (const float*)d_in[7];
    const float* ffn_b    = (const float*)d_in[8];
    float* out = (float*)d_out;

    // workspace layout (16B-aligned)
    unsigned short* Wh   = (unsigned short*)d_ws;            // N*HID bf16
    unsigned short* h_ln = Wh + (size_t)N_NODES * HID;       // N*HID bf16
    unsigned short* Wt   = h_ln + (size_t)N_NODES * HID;     // 256*256 bf16
    unsigned short* Ft   = Wt + 65536;                       // 256*256 bf16
    float* s_src  = (float*)(Ft + 65536);                    // N*HEADS
    float* s_dst  = s_src + N_NODES * HEADS;                 // N*HEADS
    float* sorted_w = s_dst + N_NODES * HEADS;               // E*HEADS
    int*   counts = (int*)(sorted_w + (size_t)E_EDGES * HEADS); // N
    int*   offsets = counts + N_NODES;                       // N+1
    int*   cursor  = offsets + N_NODES + 1;                  // N
    int*   sorted_col = cursor + N_NODES;                    // E
    int*   bsum   = sorted_col + E_EDGES;                    // 128
    int*   bscan  = bsum + 128;                              // 128

    const int NB = (N_NODES + 511) / 512;                    // 98

    hipMemsetAsync(counts, 0, N_NODES * sizeof(int), stream);
    prep_kernel<<<512, 256, 0, stream>>>(W, ffn_w, Wt, Ft);

    // Wh(bf16) = h(f32) @ W ; fused s_src/s_dst epilogue
    gemm_bres<true, false, true><<<256, 512, 0, stream>>>(
        h, Wt, nullptr, attn_fc, Wh, s_src, s_dst, N_NODES);

    hist_kernel<<<(E_EDGES + 255) / 256, 256, 0, stream>>>(erow, counts);
    scanA_kernel<<<NB, 256, 0, stream>>>(counts, bsum);
    scanB_kernel<<<1, 128, 0, stream>>>(bsum, bscan, NB);
    scanC_kernel<<<NB, 512, 0, stream>>>(counts, bscan, offsets, cursor);
    scatter_kernel<<<(E_EDGES + 255) / 256, 256, 0, stream>>>(
        erow, ecol, s_src, s_dst, cursor, sorted_col, (float4*)sorted_w);
    aggregate_ln_kernel<<<N_NODES / 4, 256, 0, stream>>>(
        Wh, sorted_w, offsets, sorted_col, ln_gamma, ln_beta, h_ln);

    // out(f32) = relu(h_ln(bf16) @ ffn_w + b)
    gemm_bres<false, true, false><<<256, 512, 0, stream>>>(
        h_ln, Ft, ffn_b, nullptr, out, nullptr, nullptr, N_NODES);
}